// Round 3
// baseline (606.374 us; speedup 1.0000x reference)
//
#include <hip/hip_runtime.h>

// ---------------------------------------------------------------------------
// DMSRStyleConv v5: style-modulated, demodulated 3x3x3 conv.
// B=8, Cin=Cout=64, 48^3 -> 46^3 VALID, fp32 in/out.
//
//   1) s_kernel  : s[b][ci]  = style @ style_w^T + style_b      (512 blk x 64)
//   2) d_kernel  : d[b][co]  = rsqrt(sum (w*s)^2 + eps)         (512 blk x 64)
//   3) wq_kernel : wq[b][kc][tap][frag][lane][8] = bf16(w*s*d)  (216 blk x 256)
//   4) xT_kernel : xT[b][z][y][x][ci] = bf16(x)  (float4 reads) (13824 blk)
//   5) conv      : implicit GEMM.
//        v5 changes (vs v4, 235 us conv, MfmaUtil 36%):
//        - co-split waves: wave = 32co x 128sp (ch = w&1 co-half,
//          zp = w>>1 z-pair). A-frag L2 traffic halves (3.0 -> 1.5 GB,
//          86 -> 43 us of L2 time) -- was nearly equal to the 94 us
//          MFMA floor and 1-deep prefetch couldn't hide its latency.
//        - T14 async-stage: kc=1 x-tile loads issued into regs at start
//          of kc=0 compute (27 taps of cover), ds_write in a midamble.
//        - launch_bounds(256,3): 3 blocks/CU (LDS 51.8 KB), VGPR <= 170.
// ---------------------------------------------------------------------------

typedef __bf16 bf16x8 __attribute__((ext_vector_type(8)));
typedef float  f32x4  __attribute__((ext_vector_type(4)));

static constexpr int   B_   = 8;
static constexpr int   S_   = 512;
static constexpr int   G_   = 48;
static constexpr int   O_   = 46;
static constexpr int   TAPS = 27;
static constexpr int   SPI  = G_ * G_ * G_;   // 110592
static constexpr int   SPO  = O_ * O_ * O_;   // 97336
static constexpr float EPSV = 1e-8f;

// workspace layout (bytes)
static constexpr size_t XT_OFF   = 0;
static constexpr size_t XT_BYTES = (size_t)B_ * SPI * 64 * 2;        // 113 MB
static constexpr size_t WQ_OFF   = XT_OFF + XT_BYTES;
static constexpr size_t WQ_BYTES = (size_t)B_ * 2 * TAPS * 64 * 32 * 2; // 1.77 MB
static constexpr size_t S_OFF    = WQ_OFF + WQ_BYTES;
static constexpr size_t D_OFF    = S_OFF + 2048;

__device__ __forceinline__ unsigned short f2bf(float f) {
    unsigned int u = __float_as_uint(f);
    u = (u + 0x7fffu + ((u >> 16) & 1u)) >> 16;
    return (unsigned short)u;
}

// ---------------------------------------------------------------------------
// 1) s[b][g] = dot(style[b,:], style_w[g,:]) + style_b[g]; grid 512, block 64
// ---------------------------------------------------------------------------
__global__ void s_kernel(const float* __restrict__ style,
                         const float* __restrict__ style_w,
                         const float* __restrict__ style_b,
                         float* __restrict__ s_out)
{
    const int bg = blockIdx.x, b = bg >> 6, g = bg & 63, l = threadIdx.x;
    const float4* sp = (const float4*)(style + b * S_);
    const float4* wp = (const float4*)(style_w + g * S_);
    const float4 a0 = sp[l * 2], a1 = sp[l * 2 + 1];
    const float4 b0 = wp[l * 2], b1 = wp[l * 2 + 1];
    float acc = a0.x * b0.x + a0.y * b0.y + a0.z * b0.z + a0.w * b0.w
              + a1.x * b1.x + a1.y * b1.y + a1.z * b1.z + a1.w * b1.w;
#pragma unroll
    for (int m = 1; m <= 32; m <<= 1) acc += __shfl_xor(acc, m);
    if (l == 0) s_out[bg] = acc + style_b[g];
}

// ---------------------------------------------------------------------------
// 2) d[b][co] = rsqrt(sum_{ci,tap}(w[co][ci][tap]*s[b][ci])^2+eps); 512 x 64
// ---------------------------------------------------------------------------
__global__ void d_kernel(const float* __restrict__ weight,
                         const float* __restrict__ s,
                         float* __restrict__ d_out)
{
    const int bc = blockIdx.x, b = bc >> 6, co = bc & 63, ci = threadIdx.x;
    const float sv = s[b * 64 + ci];
    const float* wp = weight + (co * 64 + ci) * TAPS;
    float v = 0.f;
#pragma unroll
    for (int i = 0; i < TAPS; ++i) { const float t = wp[i] * sv; v += t * t; }
#pragma unroll
    for (int m = 1; m <= 32; m <<= 1) v += __shfl_xor(v, m);
    if (ci == 0) d_out[bc] = rsqrtf(v + EPSV);
}

// ---------------------------------------------------------------------------
// 3) wq in MFMA-fragment order. Per (b,kc,tap): 2048 bf16 laid out as
//    [frag g=0..3][lane l=0..63][8 shorts]: lane l of frag g holds
//    co = g*16 + (l&15), ci_local = (l>>4)*8 + j  (j=0..7).
//    Lane-linear: conv reads A-frags straight from global, coalesced.
// ---------------------------------------------------------------------------
__global__ void wq_kernel(const float* __restrict__ weight,
                          const float* __restrict__ s,
                          const float* __restrict__ d,
                          unsigned short* __restrict__ wq)
{
    const int blk = blockIdx.x;
    const int b = blk / 27, tap = blk - b * 27;
    const int t = threadIdx.x;
#pragma unroll
    for (int it = 0; it < 2; ++it) {
        const int item = t + it * 256;          // 0..511 = kc*256 + g*64 + l
        const int kc = item >> 8;
        const int g  = (item >> 6) & 3;
        const int l  = item & 63;
        const int co = g * 16 + (l & 15);
        const int ci0 = kc * 32 + ((l >> 4) * 8);
        const float dd = d[b * 64 + co];
        unsigned int u[4];
#pragma unroll
        for (int k = 0; k < 4; ++k) {
            const int ci = ci0 + 2 * k;
            const float w0 = weight[(co * 64 + ci)     * TAPS + tap] * s[b * 64 + ci]     * dd;
            const float w1 = weight[(co * 64 + ci + 1) * TAPS + tap] * s[b * 64 + ci + 1] * dd;
            u[k] = (unsigned)f2bf(w0) | ((unsigned)f2bf(w1) << 16);
        }
        uint4 v; v.x = u[0]; v.y = u[1]; v.z = u[2]; v.w = u[3];
        *(uint4*)(wq + ((size_t)((b * 2 + kc) * 27 + tap)) * 2048 + (g * 64 + l) * 8) = v;
    }
}

// ---------------------------------------------------------------------------
// 4) x [b][ci][sp] fp32 -> xT [b][sp][ci] bf16; grid 8*1728, block 256.
//    v5: float4 global reads (4 instead of 16 loads/thread); LDS writes
//    stay scalar at stride-65 rows (2-way at most, free).
// ---------------------------------------------------------------------------
__global__ void xT_kernel(const float* __restrict__ x,
                          unsigned short* __restrict__ xT)
{
    const int blk = blockIdx.x;
    const int b = blk / 1728;
    const int sp0 = (blk - b * 1728) * 64;
    const int t = threadIdx.x;
    __shared__ float tile[64][65];

    const int cr = t >> 4;                   // 0..15
    const int s4 = (t & 15) * 4;
#pragma unroll
    for (int r = 0; r < 4; ++r) {
        const int ci = r * 16 + cr;
        const float4 v = *(const float4*)(x + ((size_t)b * 64 + ci) * SPI + sp0 + s4);
        tile[ci][s4]     = v.x;
        tile[ci][s4 + 1] = v.y;
        tile[ci][s4 + 2] = v.z;
        tile[ci][s4 + 3] = v.w;
    }
    __syncthreads();

    const int ci8 = (t & 7) * 8;
    const int spq = t >> 3;                  // 0..31
#pragma unroll
    for (int p = 0; p < 2; ++p) {
        const int sp = spq + 32 * p;
        unsigned int u[4];
#pragma unroll
        for (int k = 0; k < 4; ++k) {
            const unsigned int lo = f2bf(tile[ci8 + 2 * k][sp]);
            const unsigned int hi = f2bf(tile[ci8 + 2 * k + 1][sp]);
            u[k] = lo | (hi << 16);
        }
        uint4 v; v.x = u[0]; v.y = u[1]; v.z = u[2]; v.w = u[3];
        *(uint4*)(xT + ((size_t)b * SPI + sp0 + sp) * 64 + ci8) = v;
    }
}

// ---------------------------------------------------------------------------
// 5) conv. Block = (b, 4z x 4y x 16x) outputs x 64 cout; 4 waves; wave w:
//    co-half ch = w&1 (32 co), z-pair zp = w>>1 (2 z x 4 y x 16 x = 128 sp).
//    x-tile 18x6x6 sp x 32ci bf16 in LDS, rows stride 80 B. Per tap:
//    2 A-frag global loads (1-deep prefetch) + 8 B ds_read_b128 + 16 MFMA.
// ---------------------------------------------------------------------------
#define XST     80
#define XTILE_B (648 * 80)     // 51840

__global__ __launch_bounds__(256, 3) void conv_kernel(
    const unsigned short* __restrict__ xT,   // [8][48][48][48][64] bf16 bits
    const unsigned short* __restrict__ wq,   // [8][2][27][4][64][8] bf16 bits
    const float* __restrict__ bias,          // [64]
    float* __restrict__ out)                 // [8][64][46][46][46] fp32
{
    __shared__ __align__(16) char xs[XTILE_B];

    const int t = threadIdx.x;
    // XCD-bijective swizzle: 3456 = 8 XCD x 432; each XCD owns one batch b.
    const int p  = blockIdx.x;
    const int lg = (p & 7) * 432 + (p >> 3);
    const int xt = lg % 3;                   // 0..2
    const int r0 = lg / 3;
    const int yt = r0 % 12;                  // 0..11
    const int bz = r0 / 12;                  // 0..95
    const int b  = bz / 12, zt = bz - b * 12;
    const int x0 = xt * 16;                  // {0,16,32}; ox>=46 masked
    const int y0 = (yt < 11) ? yt * 4 : 42;  // overlap tiles: dup stores identical
    const int z0 = (zt < 11) ? zt * 4 : 42;

    const unsigned short* const xb = xT + (size_t)b * (SPI * 64);
    const unsigned short* const wb = wq + (size_t)b * (2 * TAPS * 2048);

    const int w = t >> 6, l = t & 63, kg = l >> 4, l16 = l & 15;
    const int ch = w & 1, zp = w >> 1;
    // A-frag base: + kt*2048 + cf*512 shorts
    const unsigned short* const wa = wb + ch * 1024 + l * 8;
    // B-frag base: row (2*zp)*108 + l16, k-slot kg
    const int bbase = (zp * 216 + l16) * XST + kg * 16;
    // B n-frag row offsets: nf = zl*4 + yy -> (zl*108 + yy*18)*80
    constexpr int FOFF[8] = {0, 1440, 2880, 4320, 8640, 10080, 11520, 12960};

    f32x4 acc[16];
#pragma unroll
    for (int i = 0; i < 16; ++i) acc[i] = (f32x4){0.f, 0.f, 0.f, 0.f};

    // ---- item -> global src addr for x staging ---------------------------
    auto x_src = [&](int i, int kc) -> const uint4* {
        const int sp = i >> 2, cg = i & 3;
        const int iz = sp / 108;
        const int r1 = sp - iz * 108;
        const int iy = r1 / 18;
        const int ix = r1 - iy * 18;
        int gx = x0 + ix; if (gx > 47) gx = 47;      // clamp (masked outputs)
        return (const uint4*)(xb +
            ((((z0 + iz) * 48) + (y0 + iy)) * 48 + gx) * 64 + kc * 32 + cg * 8);
    };

    // ---- stage kc=0 directly ---------------------------------------------
#pragma unroll
    for (int j = 0; j < 10; ++j) {
        const int i = t + j * 256;
        const uint4 v = *x_src(i, 0);
        *(uint4*)(xs + (i >> 2) * XST + (i & 3) * 16) = v;
    }
    if (t < 32) {
        const int i = 2560 + t;
        const uint4 v = *x_src(i, 0);
        *(uint4*)(xs + (i >> 2) * XST + (i & 3) * 16) = v;
    }

    // prefetch A for kt=0
    bf16x8 a0 = *(const bf16x8*)(wa);
    bf16x8 a1 = *(const bf16x8*)(wa + 512);

    __syncthreads();                         // kc0 x-tile visible

    // ---- T14: issue kc=1 stage loads (held in regs across kc0 compute) ---
    uint4 pv[10];
#pragma unroll
    for (int j = 0; j < 10; ++j)
        pv[j] = *x_src(t + j * 256, 1);

    auto tap_body = [&](int kt, int ktn) {
        const bf16x8 n0 = *(const bf16x8*)(wa + (size_t)ktn * 2048);
        const bf16x8 n1 = *(const bf16x8*)(wa + (size_t)ktn * 2048 + 512);
        const int tap = (kt >= 27) ? kt - 27 : kt;
        const int kz = tap / 9;
        const int r2 = tap - kz * 9;
        const int ky = r2 / 3;
        const int kx = r2 - ky * 3;
        const int toff = (kz * 108 + ky * 18 + kx) * XST;
#pragma unroll
        for (int nf = 0; nf < 8; ++nf) {
            const bf16x8 bv = *(const bf16x8*)(xs + toff + bbase + FOFF[nf]);
            acc[nf]     = __builtin_amdgcn_mfma_f32_16x16x32_bf16(a0, bv, acc[nf],     0, 0, 0);
            acc[8 + nf] = __builtin_amdgcn_mfma_f32_16x16x32_bf16(a1, bv, acc[8 + nf], 0, 0, 0);
        }
        a0 = n0; a1 = n1;
    };

    // ---- kc=0 taps (prefetch runs into kt=27 = kc1 tap0) -----------------
#pragma unroll 1
    for (int kt = 0; kt < 27; ++kt)
        tap_body(kt, kt + 1);

    // ---- midamble: retire kc1 stage regs into LDS ------------------------
    __syncthreads();                         // all kc0 readers done
#pragma unroll
    for (int j = 0; j < 10; ++j) {
        const int i = t + j * 256;
        *(uint4*)(xs + (i >> 2) * XST + (i & 3) * 16) = pv[j];
    }
    if (t < 32) {                            // 32-item tail loaded here
        const int i = 2560 + t;
        const uint4 v = *x_src(i, 1);
        *(uint4*)(xs + (i >> 2) * XST + (i & 3) * 16) = v;
    }
    __syncthreads();                         // kc1 x-tile visible

    // ---- kc=1 taps -------------------------------------------------------
#pragma unroll 1
    for (int kt = 27; kt < 54; ++kt)
        tap_body(kt, (kt + 1 < 54) ? kt + 1 : 53);

    // ---- epilogue: C/D col = l16 = dx (n), row = kg*4+r = co%16 ----------
    const size_t ob = (size_t)b * 64 * SPO;
    const int ox = x0 + l16;
    if (ox < O_) {
#pragma unroll
        for (int cf = 0; cf < 2; ++cf) {
#pragma unroll
            for (int nf = 0; nf < 8; ++nf) {
                const int oz = z0 + 2 * zp + (nf >> 2);
                const int oy = y0 + (nf & 3);
                const f32x4 v = acc[cf * 8 + nf];
                const size_t so = (size_t)oz * 2116 + oy * 46 + ox;
#pragma unroll
                for (int r = 0; r < 4; ++r) {
                    const int co = ch * 32 + cf * 16 + kg * 4 + r;
                    out[ob + (size_t)co * SPO + so] = v[r] + bias[co];
                }
            }
        }
    }
}

// ---------------------------------------------------------------------------
extern "C" void kernel_launch(void* const* d_in, const int* in_sizes, int n_in,
                              void* d_out, int out_size, void* d_ws, size_t ws_size,
                              hipStream_t stream)
{
    const float* x       = (const float*)d_in[0];
    const float* style   = (const float*)d_in[1];
    const float* weight  = (const float*)d_in[2];
    const float* bias    = (const float*)d_in[3];
    const float* style_w = (const float*)d_in[4];
    const float* style_b = (const float*)d_in[5];
    float* out = (float*)d_out;

    char* ws = (char*)d_ws;
    unsigned short* xT  = (unsigned short*)(ws + XT_OFF);
    unsigned short* wqp = (unsigned short*)(ws + WQ_OFF);
    float* sbuf = (float*)(ws + S_OFF);
    float* dbuf = (float*)(ws + D_OFF);

    hipLaunchKernelGGL(s_kernel, dim3(512), dim3(64), 0, stream,
                       style, style_w, style_b, sbuf);
    hipLaunchKernelGGL(d_kernel, dim3(512), dim3(64), 0, stream,
                       weight, sbuf, dbuf);
    hipLaunchKernelGGL(wq_kernel, dim3(216), dim3(256), 0, stream,
                       weight, sbuf, dbuf, wqp);
    hipLaunchKernelGGL(xT_kernel, dim3(B_ * (SPI / 64)), dim3(256), 0, stream,
                       x, xT);
    hipLaunchKernelGGL(conv_kernel, dim3(3456), dim3(256), 0, stream,
                       xT, wqp, bias, out);
}